// Round 10
// baseline (404.741 us; speedup 1.0000x reference)
//
#include <hip/hip_runtime.h>

// HistogramLoss on MI355X — Round 10: ABLATION. Real path identical to R9
// (V0 -> partial -> reduce -> finalize; absmax 0.0). Probe dispatches V1-V4
// write to scratch and isolate: V1=GEMM-only, V2=epilogue-only(+atomics),
// V3=scaffolding-only, V4=epilogue-only(no atomics). rocprof per-dispatch
// durations give the component costs that 5 rounds of modeling failed to.

#define N_PTS   4096
#define DIM     512
#define TSIZE   151
#define HALF_T  75
#define BM      128
#define BK      64
#define NSTEP   24                  // K' = 3*512 / BK
#define NPAIR   528
#define P_TOTAL 8386560u
#define STEPF   (2.0f / 150.0f)
#define STEPINV 75.0f
#define NCOPY   8
#define HSTRIDE 309
#define GRID    576
#define NROWS   (2 * TSIZE + 1)

typedef short bfrag __attribute__((ext_vector_type(8)));
typedef float ffrag __attribute__((ext_vector_type(4)));
typedef unsigned short u16;
typedef unsigned int   u32;

__device__ __forceinline__ ffrag mfma16(bfrag a, bfrag b, ffrag c) {
  return __builtin_amdgcn_mfma_f32_16x16x32_bf16(a, b, c, 0, 0, 0);
}

__device__ __forceinline__ void split4(float4 v, uint2* hi, uint2* lo) {
  u32 u0 = __float_as_uint(v.x), u1 = __float_as_uint(v.y);
  u32 u2 = __float_as_uint(v.z), u3 = __float_as_uint(v.w);
  float r0 = v.x - __uint_as_float(u0 & 0xFFFF0000u);
  float r1 = v.y - __uint_as_float(u1 & 0xFFFF0000u);
  float r2 = v.z - __uint_as_float(u2 & 0xFFFF0000u);
  float r3 = v.w - __uint_as_float(u3 & 0xFFFF0000u);
  hi->x = (u0 >> 16) | (u1 & 0xFFFF0000u);
  hi->y = (u2 >> 16) | (u3 & 0xFFFF0000u);
  lo->x = (__float_as_uint(r0) >> 16) | (__float_as_uint(r1) & 0xFFFF0000u);
  lo->y = (__float_as_uint(r2) >> 16) | (__float_as_uint(r3) & 0xFFFF0000u);
}

__device__ __forceinline__ bool tile_decode(int bid, int* bi_, int* bj_) {
  const int xcd = bid & 7, slot = bid >> 3;
  if (xcd < 6) {
    if (slot >= 64) return false;
    const int BA[6] = {0, 0, 0, 1, 1, 2};
    const int BB[6] = {1, 2, 3, 2, 3, 3};
    *bi_ = BA[xcd] * 8 + (slot >> 3);
    *bj_ = BB[xcd] * 8 + (slot & 7);
  } else {
    int p = slot;
    int band = (xcd - 6) * 2 + (p >= 36 ? 1 : 0);
    if (p >= 36) p -= 36;
    int rem = p, cnt = 8, ii = 0;
    while (rem >= cnt) { rem -= cnt; --cnt; ++ii; }
    *bi_ = band * 8 + ii;
    *bj_ = band * 8 + ii + rem;
  }
  return true;
}

__device__ __forceinline__ int pair_index(int bi, int bj) {
  return bi * 32 - bi * (bi - 1) / 2 + (bj - bi);
}

__device__ __forceinline__ void stage_step(
    int s, u16* Ad, u16* Bd,
    const u16* __restrict__ Fhi, const u16* __restrict__ Flo,
    int rowA, int rowB, int w, int rseg, int swzk)
{
  const int region = s >> 3;
  const int k0 = (s & 7) * BK;
  const u16* ap = (region == 1) ? Flo : Fhi;
  const u16* bp = (region == 2) ? Flo : Fhi;
  #pragma unroll
  for (int g = 0; g < 4; ++g) {
    int seg = w * 4 + g;
    int row = seg * 8 + rseg;
    size_t ga = (size_t)(rowA + row) * DIM + k0 + swzk;
    size_t gb = (size_t)(rowB + row) * DIM + k0 + swzk;
    __builtin_amdgcn_global_load_lds(
        (const __attribute__((address_space(1))) unsigned int*)(ap + ga),
        (__attribute__((address_space(3))) unsigned int*)(Ad + seg * 512),
        16, 0, 0);
    __builtin_amdgcn_global_load_lds(
        (const __attribute__((address_space(1))) unsigned int*)(bp + gb),
        (__attribute__((address_space(3))) unsigned int*)(Bd + seg * 512),
        16, 0, 0);
  }
}

__device__ __forceinline__ void compute_step(
    const u16* As, const u16* Bs, ffrag (&acc)[4][4],
    int wy, int wx, int l4, int l16)
{
  const int swz = (l16 & 7) << 3;
  #pragma unroll
  for (int ks = 0; ks < 2; ++ks) {
    bfrag a[4], b[4];
    #pragma unroll
    for (int f = 0; f < 4; ++f) {
      int ra = wy * 64 + f * 16 + l16;
      int rb = wx * 64 + f * 16 + l16;
      int ko = (ks * 32 + l4 * 8) ^ swz;
      a[f] = *(const bfrag*)(As + ra * BK + ko);
      b[f] = *(const bfrag*)(Bs + rb * BK + ko);
    }
    #pragma unroll
    for (int fj = 0; fj < 4; ++fj)
      #pragma unroll
      for (int fi = 0; fi < 4; ++fi)
        acc[fi][fj] = mfma16(a[fi], b[fj], acc[fi][fj]);
  }
}

// ATOM=1: real LDS atomics. ATOM=0: identical bin math, asm-sunk (rule #17).
template <int ATOM>
__device__ __forceinline__ void bin_epilogue(
    const ffrag (&acc)[4][4], float* h, const int* clsA, const int* clsB,
    int wy, int wx, int l4, int l16, bool diag, u32* myPos)
{
  float sink = 0.0f;
  #pragma unroll
  for (int fi = 0; fi < 4; ++fi) {
    #pragma unroll
    for (int fj = 0; fj < 4; ++fj) {
      #pragma unroll
      for (int r = 0; r < 4; ++r) {
        int li = wy * 64 + fi * 16 + l4 * 4 + r;
        int lj = wx * 64 + fj * 16 + l16;
        if (diag && li >= lj) continue;
        float s  = acc[fi][fj][r];
        float jf = floorf(s * STEPINV);
        int   jb = (int)jf + HALF_T;
        float f  = jf * STEPF;
        float wa = (s - f) * STEPINV;
        float wb = (f + STEPF - s) * STEPINV;
        bool  pos = (clsA[li] == clsB[lj]);
        *myPos += pos ? 1u : 0u;
        int off = pos ? 0 : TSIZE;
        if (ATOM) {
          if (jb >= 0 && jb < TSIZE)         unsafeAtomicAdd(h + off + jb, wa);
          if (jb + 1 >= 0 && jb + 1 < TSIZE) unsafeAtomicAdd(h + off + jb + 1, wb);
        } else {
          sink += (jb >= 0 && jb < TSIZE) ? wa * (float)(off + jb) : 0.0f;
          sink += (jb + 1 < TSIZE) ? wb * (float)(off + jb + 1) : 0.0f;
        }
      }
    }
  }
  if (!ATOM) asm volatile("" :: "v"(sink));   // keep bin math live, no DCE
}

__global__ __launch_bounds__(256) void presplit(
    const float* __restrict__ F, u16* __restrict__ Fhi, u16* __restrict__ Flo)
{
  int u = blockIdx.x * 256 + threadIdx.x;
  int row = u >> 6, kb = u & 63;
  const float* src = F + (size_t)row * DIM + kb * 8;
  float4 v0 = *(const float4*)(src);
  float4 v1 = *(const float4*)(src + 4);
  uint2 h0, l0, h1, l1;
  split4(v0, &h0, &l0);
  split4(v1, &h1, &l1);
  uint4 hv; hv.x = h0.x; hv.y = h0.y; hv.z = h1.x; hv.w = h1.y;
  uint4 lv; lv.x = l0.x; lv.y = l0.y; lv.z = l1.x; lv.w = l1.y;
  size_t dst = (size_t)row * DIM + kb * 8;
  *(uint4*)(Fhi + dst) = hv;
  *(uint4*)(Flo + dst) = lv;
}

// V: 0=full(real)  1=GEMM-only  2=EPI-only(+atomic)  3=scaffold  4=EPI-only(no atomic)
template <int V>
__global__ __launch_bounds__(256, 3) void hist_mfma(
    const u16* __restrict__ Fhi, const u16* __restrict__ Flo,
    const int* __restrict__ cls, float* __restrict__ partial)
{
  __shared__ __align__(16) u16 As[BM * BK];
  __shared__ __align__(16) u16 Bs[BM * BK];
  __shared__ float hist[NCOPY * HSTRIDE];
  __shared__ int clsA[BM], clsB[BM];
  __shared__ u32 posCount;

  int bi, bj;
  if (!tile_decode((int)blockIdx.x, &bi, &bj)) return;
  const int t = threadIdx.x;
  const int rowA = bi * BM, rowB = bj * BM;

  As[t] = (u16)t; Bs[t] = (u16)t;            // pin LDS arrays in all variants
  for (int i = t; i < NCOPY * HSTRIDE; i += 256) hist[i] = 0.0f;
  if (t < BM) clsA[t] = cls[rowA + t];
  else        clsB[t - BM] = cls[rowB + (t - BM)];
  if (t == 0) posCount = 0u;

  const int lane = t & 63, w = t >> 6;
  const int wy = w >> 1, wx = w & 1;
  const int l4 = lane >> 4, l16 = lane & 15;
  const int rseg = lane >> 3;
  const int swzk = ((lane & 7) ^ (lane >> 3)) << 3;

  ffrag acc[4][4] = {};

  if (V == 0 || V == 1) {
    #pragma unroll 1
    for (int s = 0; s < NSTEP; ++s) {
      __syncthreads();
      stage_step(s, As, Bs, Fhi, Flo, rowA, rowB, w, rseg, swzk);
      __syncthreads();
      compute_step(As, Bs, acc, wy, wx, l4, l16);
    }
  } else {
    // synthetic similarities, hot-bin realistic (|s| <~ 0.1), cheap hash
    #pragma unroll
    for (int fi = 0; fi < 4; ++fi)
      #pragma unroll
      for (int fj = 0; fj < 4; ++fj)
        #pragma unroll
        for (int r = 0; r < 4; ++r) {
          u32 hsh = ((u32)(t + 1) * 2654435761u) ^ ((fi * 97 + fj * 131 + r * 17) * 2246822519u);
          acc[fi][fj][r] = ((hsh >> 8) & 0xFFFF) * (0.2f / 65536.0f) - 0.1f;
        }
    __syncthreads();
  }

  u32 myPos = 0;
  float* h = hist + (lane & 7) * HSTRIDE;
  if (V == 0 || V == 2) bin_epilogue<1>(acc, h, clsA, clsB, wy, wx, l4, l16, bi == bj, &myPos);
  if (V == 4)           bin_epilogue<0>(acc, h, clsA, clsB, wy, wx, l4, l16, bi == bj, &myPos);
  if (V == 1) {                              // sink acc so MFMAs aren't DCE'd
    float sink = 0.0f;
    #pragma unroll
    for (int fi = 0; fi < 4; ++fi)
      #pragma unroll
      for (int fj = 0; fj < 4; ++fj)
        #pragma unroll
        for (int r = 0; r < 4; ++r) sink += acc[fi][fj][r];
    asm volatile("" :: "v"(sink));
  }
  atomicAdd(&posCount, myPos);
  __syncthreads();

  const int p = pair_index(bi, bj);
  for (int i = t; i < 2 * TSIZE; i += 256) {
    float v = 0.0f;
    #pragma unroll
    for (int c = 0; c < NCOPY; ++c) v += hist[c * HSTRIDE + i];
    partial[(size_t)i * NPAIR + p] = v;
  }
  if (t == 0) partial[(size_t)(2 * TSIZE) * NPAIR + p] = (float)posCount;
}

__global__ __launch_bounds__(256) void reduce_partials(
    const float* __restrict__ partial, float* __restrict__ g_hist)
{
  const int wv = blockIdx.x * 4 + (threadIdx.x >> 6);
  const int lane = threadIdx.x & 63;
  if (wv >= NROWS) return;
  float s = 0.0f;
  for (int p = lane; p < NPAIR; p += 64) s += partial[(size_t)wv * NPAIR + p];
  #pragma unroll
  for (int o = 32; o > 0; o >>= 1) s += __shfl_down(s, o);
  if (lane == 0) g_hist[wv] = s;
}

__global__ __launch_bounds__(256) void finalize(
    const float* __restrict__ g_hist, float* __restrict__ out)
{
  __shared__ float hp[TSIZE];
  __shared__ float hn[TSIZE];
  __shared__ float red[4];
  const int t = threadIdx.x;
  const float Np = g_hist[2 * TSIZE];
  const float Nn = (float)P_TOTAL - Np;
  if (t < TSIZE) {
    hp[t] = g_hist[t] / Np;
    hn[t] = g_hist[TSIZE + t] / Nn;
  }
  __syncthreads();
  for (int off = 1; off < TSIZE; off <<= 1) {
    float v = 0.0f;
    if (t < TSIZE && t >= off) v = hp[t - off];
    __syncthreads();
    if (t < TSIZE) hp[t] += v;
    __syncthreads();
  }
  float term = (t < TSIZE) ? hn[t] * hp[t] : 0.0f;
  #pragma unroll
  for (int o = 32; o > 0; o >>= 1) term += __shfl_down(term, o);
  if ((t & 63) == 0) red[t >> 6] = term;
  __syncthreads();
  if (t == 0) *out = red[0] + red[1] + red[2] + red[3];
}

extern "C" void kernel_launch(void* const* d_in, const int* in_sizes, int n_in,
                              void* d_out, int out_size, void* d_ws, size_t ws_size,
                              hipStream_t stream) {
  const float* F   = (const float*)d_in[0];
  const int*   cls = (const int*)d_in[1];
  float* g_hist = (float*)d_ws;
  float* out = (float*)d_out;

  const size_t offH     = 65536;
  const size_t bytesP   = (size_t)N_PTS * DIM * sizeof(u16);
  const size_t offPar   = offH + 2 * bytesP;
  const size_t bytesPar = (size_t)NROWS * NPAIR * sizeof(float);
  const size_t offProbe = offPar + bytesPar;
  u16* Fhi = (u16*)((char*)d_ws + offH);
  u16* Flo = (u16*)((char*)d_ws + offH + bytesP);
  float* partial = (float*)((char*)d_ws + offPar);

  presplit<<<(N_PTS * 64) / 256, 256, 0, stream>>>(F, Fhi, Flo);
  hist_mfma<0><<<GRID, 256, 0, stream>>>(Fhi, Flo, cls, partial);
  reduce_partials<<<(NROWS + 3) / 4, 256, 0, stream>>>(partial, g_hist);
  finalize<<<1, 256, 0, stream>>>(g_hist, out);

  // ---- ablation probes (scratch output; removed next round) ----
  if (ws_size >= offProbe + bytesPar) {
    float* probe = (float*)((char*)d_ws + offProbe);
    hist_mfma<1><<<GRID, 256, 0, stream>>>(Fhi, Flo, cls, probe);  // GEMM only
    hist_mfma<2><<<GRID, 256, 0, stream>>>(Fhi, Flo, cls, probe);  // EPI only (+atomic)
    hist_mfma<3><<<GRID, 256, 0, stream>>>(Fhi, Flo, cls, probe);  // scaffold only
    hist_mfma<4><<<GRID, 256, 0, stream>>>(Fhi, Flo, cls, probe);  // EPI only (no atomic)
  }
}

// Round 11
// 293.376 us; speedup vs baseline: 1.3796x; 1.3796x over previous
//
#include <hip/hip_runtime.h>

// HistogramLoss on MI355X — fused pairwise-cosine + soft-histogram + loss.
// Round 11: counted-vmcnt deep pipeline (T4). R10 ablation proved the K-loop
// is 100% of the wall; the 2-phase vmcnt(0) drain starved outstanding-bytes
// (Little's law: ~3 KB avg in flight -> ~2.8 TB/s effective on 405 MB).
// Now: 3 LDS buffers, one raw s_barrier per step, s_waitcnt vmcnt(8) so the
// next step's 8 DMA loads stay in flight across barrier+compute. Addressing,
// swizzle, and epilogue math verbatim from the absmax-0.0 R8/R9 kernel.

#define N_PTS   4096
#define DIM     512
#define TSIZE   151
#define HALF_T  75
#define BM      128
#define BK      64
#define NSTEP   24                  // K' = 3*512 / BK
#define NBUF    3
#define NPAIR   528
#define P_TOTAL 8386560u
#define STEPF   (2.0f / 150.0f)
#define STEPINV 75.0f
#define NCOPY   8
#define HSTRIDE 309
#define GRID    576
#define NROWS   (2 * TSIZE + 1)

typedef short bfrag __attribute__((ext_vector_type(8)));
typedef float ffrag __attribute__((ext_vector_type(4)));
typedef unsigned short u16;
typedef unsigned int   u32;

__device__ __forceinline__ ffrag mfma16(bfrag a, bfrag b, ffrag c) {
  return __builtin_amdgcn_mfma_f32_16x16x32_bf16(a, b, c, 0, 0, 0);
}

__device__ __forceinline__ void split4(float4 v, uint2* hi, uint2* lo) {
  u32 u0 = __float_as_uint(v.x), u1 = __float_as_uint(v.y);
  u32 u2 = __float_as_uint(v.z), u3 = __float_as_uint(v.w);
  float r0 = v.x - __uint_as_float(u0 & 0xFFFF0000u);
  float r1 = v.y - __uint_as_float(u1 & 0xFFFF0000u);
  float r2 = v.z - __uint_as_float(u2 & 0xFFFF0000u);
  float r3 = v.w - __uint_as_float(u3 & 0xFFFF0000u);
  hi->x = (u0 >> 16) | (u1 & 0xFFFF0000u);
  hi->y = (u2 >> 16) | (u3 & 0xFFFF0000u);
  lo->x = (__float_as_uint(r0) >> 16) | (__float_as_uint(r1) & 0xFFFF0000u);
  lo->y = (__float_as_uint(r2) >> 16) | (__float_as_uint(r3) & 0xFFFF0000u);
}

__device__ __forceinline__ bool tile_decode(int bid, int* bi_, int* bj_) {
  const int xcd = bid & 7, slot = bid >> 3;
  if (xcd < 6) {
    if (slot >= 64) return false;
    const int BA[6] = {0, 0, 0, 1, 1, 2};
    const int BB[6] = {1, 2, 3, 2, 3, 3};
    *bi_ = BA[xcd] * 8 + (slot >> 3);
    *bj_ = BB[xcd] * 8 + (slot & 7);
  } else {
    int p = slot;
    int band = (xcd - 6) * 2 + (p >= 36 ? 1 : 0);
    if (p >= 36) p -= 36;
    int rem = p, cnt = 8, ii = 0;
    while (rem >= cnt) { rem -= cnt; --cnt; ++ii; }
    *bi_ = band * 8 + ii;
    *bj_ = band * 8 + ii + rem;
  }
  return true;
}

__device__ __forceinline__ int pair_index(int bi, int bj) {
  return bi * 32 - bi * (bi - 1) / 2 + (bj - bi);
}

// stage one 128x64 A+B tile for virtual-K step s (8 gload_lds per wave).
__device__ __forceinline__ void stage_step(
    int s, u16* Ad, u16* Bd,
    const u16* __restrict__ Fhi, const u16* __restrict__ Flo,
    int rowA, int rowB, int w, int rseg, int swzk)
{
  const int region = s >> 3;                 // 0: hi*hi, 1: lo*hi, 2: hi*lo
  const int k0 = (s & 7) * BK;
  const u16* ap = (region == 1) ? Flo : Fhi;
  const u16* bp = (region == 2) ? Flo : Fhi;
  #pragma unroll
  for (int g = 0; g < 4; ++g) {
    int seg = w * 4 + g;
    int row = seg * 8 + rseg;
    size_t ga = (size_t)(rowA + row) * DIM + k0 + swzk;
    size_t gb = (size_t)(rowB + row) * DIM + k0 + swzk;
    __builtin_amdgcn_global_load_lds(
        (const __attribute__((address_space(1))) unsigned int*)(ap + ga),
        (__attribute__((address_space(3))) unsigned int*)(Ad + seg * 512),
        16, 0, 0);
    __builtin_amdgcn_global_load_lds(
        (const __attribute__((address_space(1))) unsigned int*)(bp + gb),
        (__attribute__((address_space(3))) unsigned int*)(Bd + seg * 512),
        16, 0, 0);
  }
}

__device__ __forceinline__ void compute_step(
    const u16* As, const u16* Bs, ffrag (&acc)[4][4],
    int wy, int wx, int l4, int l16)
{
  const int swz = (l16 & 7) << 3;
  #pragma unroll
  for (int ks = 0; ks < 2; ++ks) {
    bfrag a[4], b[4];
    #pragma unroll
    for (int f = 0; f < 4; ++f) {
      int ra = wy * 64 + f * 16 + l16;
      int rb = wx * 64 + f * 16 + l16;
      int ko = (ks * 32 + l4 * 8) ^ swz;
      a[f] = *(const bfrag*)(As + ra * BK + ko);
      b[f] = *(const bfrag*)(Bs + rb * BK + ko);
    }
    #pragma unroll
    for (int fj = 0; fj < 4; ++fj)
      #pragma unroll
      for (int fi = 0; fi < 4; ++fi)
        acc[fi][fj] = mfma16(a[fi], b[fj], acc[fi][fj]);
  }
}

__device__ __forceinline__ void bin_epilogue(
    const ffrag (&acc)[4][4], float* h, const int* clsA, const int* clsB,
    int wy, int wx, int l4, int l16, bool diag, u32* myPos)
{
  #pragma unroll
  for (int fi = 0; fi < 4; ++fi) {
    #pragma unroll
    for (int fj = 0; fj < 4; ++fj) {
      #pragma unroll
      for (int r = 0; r < 4; ++r) {
        int li = wy * 64 + fi * 16 + l4 * 4 + r;
        int lj = wx * 64 + fj * 16 + l16;
        if (diag && li >= lj) continue;
        float s  = acc[fi][fj][r];
        float jf = floorf(s * STEPINV);
        int   jb = (int)jf + HALF_T;
        float f  = jf * STEPF;
        float wa = (s - f) * STEPINV;
        float wb = (f + STEPF - s) * STEPINV;
        bool  pos = (clsA[li] == clsB[lj]);
        *myPos += pos ? 1u : 0u;
        int off = pos ? 0 : TSIZE;
        if (jb >= 0 && jb < TSIZE)         unsafeAtomicAdd(h + off + jb, wa);
        if (jb + 1 >= 0 && jb + 1 < TSIZE) unsafeAtomicAdd(h + off + jb + 1, wb);
      }
    }
  }
}

__global__ __launch_bounds__(256) void presplit(
    const float* __restrict__ F, u16* __restrict__ Fhi, u16* __restrict__ Flo)
{
  int u = blockIdx.x * 256 + threadIdx.x;
  int row = u >> 6, kb = u & 63;
  const float* src = F + (size_t)row * DIM + kb * 8;
  float4 v0 = *(const float4*)(src);
  float4 v1 = *(const float4*)(src + 4);
  uint2 h0, l0, h1, l1;
  split4(v0, &h0, &l0);
  split4(v1, &h1, &l1);
  uint4 hv; hv.x = h0.x; hv.y = h0.y; hv.z = h1.x; hv.w = h1.y;
  uint4 lv; lv.x = l0.x; lv.y = l0.y; lv.z = l1.x; lv.w = l1.y;
  size_t dst = (size_t)row * DIM + kb * 8;
  *(uint4*)(Fhi + dst) = hv;
  *(uint4*)(Flo + dst) = lv;
}

// ---- pass 2: 3-buffer counted-vmcnt pipelined MFMA GEMM + binning ----
__global__ __launch_bounds__(256) void hist_mfma(
    const u16* __restrict__ Fhi, const u16* __restrict__ Flo,
    const int* __restrict__ cls, float* __restrict__ partial)
{
  __shared__ __align__(16) u16 AS[NBUF][BM * BK];   // 3 x 16 KB
  __shared__ __align__(16) u16 BS[NBUF][BM * BK];   // 3 x 16 KB
  __shared__ float hist[NCOPY * HSTRIDE];           // 9.9 KB
  __shared__ int clsA[BM], clsB[BM];
  __shared__ u32 posCount;

  int bi, bj;
  if (!tile_decode((int)blockIdx.x, &bi, &bj)) return;
  const int t = threadIdx.x;
  const int rowA = bi * BM, rowB = bj * BM;

  for (int i = t; i < NCOPY * HSTRIDE; i += 256) hist[i] = 0.0f;
  if (t < BM) clsA[t] = cls[rowA + t];
  else        clsB[t - BM] = cls[rowB + (t - BM)];
  if (t == 0) posCount = 0u;

  const int lane = t & 63, w = t >> 6;
  const int wy = w >> 1, wx = w & 1;
  const int l4 = lane >> 4, l16 = lane & 15;
  const int rseg = lane >> 3;
  const int swzk = ((lane & 7) ^ (lane >> 3)) << 3;

  ffrag acc[4][4] = {};

  // prologue: buffer 0 in flight
  stage_step(0, AS[0], BS[0], Fhi, Flo, rowA, rowB, w, rseg, swzk);

  #pragma unroll 1
  for (int s = 0; s < NSTEP; ++s) {
    if (s + 1 < NSTEP) {
      stage_step(s + 1, AS[(s + 1) % NBUF], BS[(s + 1) % NBUF],
                 Fhi, Flo, rowA, rowB, w, rseg, swzk);
      // wait for buffer s only; buffer s+1's 8 loads stay in flight (T4)
      asm volatile("s_waitcnt vmcnt(8)" ::: "memory");
    } else {
      asm volatile("s_waitcnt vmcnt(0)" ::: "memory");
    }
    __builtin_amdgcn_s_barrier();
    compute_step(AS[s % NBUF], BS[s % NBUF], acc, wy, wx, l4, l16);
  }

  u32 myPos = 0;
  float* h = hist + (lane & 7) * HSTRIDE;
  bin_epilogue(acc, h, clsA, clsB, wy, wx, l4, l16, bi == bj, &myPos);
  atomicAdd(&posCount, myPos);
  __syncthreads();

  const int p = pair_index(bi, bj);
  for (int i = t; i < 2 * TSIZE; i += 256) {
    float v = 0.0f;
    #pragma unroll
    for (int c = 0; c < NCOPY; ++c) v += hist[c * HSTRIDE + i];
    partial[(size_t)i * NPAIR + p] = v;
  }
  if (t == 0) partial[(size_t)(2 * TSIZE) * NPAIR + p] = (float)posCount;
}

// ---- pass 3: partial-column reduce + cumsum + dot, single dispatch ----
__global__ __launch_bounds__(1024) void reduce_finalize(
    const float* __restrict__ partial, float* __restrict__ out)
{
  __shared__ float hsum[NROWS];
  __shared__ float hp[TSIZE];
  __shared__ float hn[TSIZE];
  __shared__ float red[16];
  const int t = threadIdx.x, wv = t >> 6, lane = t & 63;

  for (int r = wv; r < NROWS; r += 16) {
    float s = 0.0f;
    for (int p = lane; p < NPAIR; p += 64) s += partial[(size_t)r * NPAIR + p];
    #pragma unroll
    for (int o = 32; o > 0; o >>= 1) s += __shfl_down(s, o);
    if (lane == 0) hsum[r] = s;
  }
  __syncthreads();

  const float Np = hsum[2 * TSIZE];
  const float Nn = (float)P_TOTAL - Np;
  if (t < TSIZE) {
    hp[t] = hsum[t] / Np;
    hn[t] = hsum[TSIZE + t] / Nn;
  }
  __syncthreads();
  for (int off = 1; off < TSIZE; off <<= 1) {
    float v = 0.0f;
    if (t < TSIZE && t >= off) v = hp[t - off];
    __syncthreads();
    if (t < TSIZE) hp[t] += v;
    __syncthreads();
  }
  float term = (t < TSIZE) ? hn[t] * hp[t] : 0.0f;
  #pragma unroll
  for (int o = 32; o > 0; o >>= 1) term += __shfl_down(term, o);
  if ((t & 63) == 0) red[t >> 6] = term;
  __syncthreads();
  if (t == 0) {
    float s = 0.0f;
    #pragma unroll
    for (int i = 0; i < 16; ++i) s += red[i];
    *out = s;
  }
}

extern "C" void kernel_launch(void* const* d_in, const int* in_sizes, int n_in,
                              void* d_out, int out_size, void* d_ws, size_t ws_size,
                              hipStream_t stream) {
  const float* F   = (const float*)d_in[0];
  const int*   cls = (const int*)d_in[1];
  float* out = (float*)d_out;

  const size_t offH   = 65536;
  const size_t bytesP = (size_t)N_PTS * DIM * sizeof(u16);       // 4 MB
  const size_t offPar = offH + 2 * bytesP;                       // 8.45 MB
  u16* Fhi = (u16*)((char*)d_ws + offH);
  u16* Flo = (u16*)((char*)d_ws + offH + bytesP);
  float* partial = (float*)((char*)d_ws + offPar);               // 640 KB

  presplit<<<(N_PTS * 64) / 256, 256, 0, stream>>>(F, Fhi, Flo);
  hist_mfma<<<GRID, 256, 0, stream>>>(Fhi, Flo, cls, partial);
  reduce_finalize<<<1, 1024, 0, stream>>>(partial, out);
}